// Round 14
// baseline (326.850 us; speedup 1.0000x reference)
//
#include <hip/hip_runtime.h>
#include <cstddef>

// LiteMLA: qkv GEMM (split-fp16 MFMA, 3-pass) -> dwconv5x5+groupmix ->
// linear attention -> proj GEMM (split-A fp16 MFMA, 2-pass) + BN.
// B=4, C=512, H=W=64, N=4096, heads=128, 24 ch/head.
//
// Precision design: attention's relu(q)/relu(k) sign decisions amplify GEMM
// rounding (bf16 1-pass -> absmax 0.07). Split fp16 (hi+lo) gives ~2^-22
// rel GEMM error on qkv; proj is linear so split-A only suffices.
//
// GEMM v12 (FINAL; R13 post-mortem): R13 tried direct global->VGPR B loads
// mixed with GLL in one counted-vmcnt FIFO and raced under graph replay:
// vmcnt retirement is in-order only WITHIN a VMEM type; global_load (VGPR)
// and global_load_lds (LDS-DMA) can retire out-of-order, so WAIT_VM(N)
// cannot select "the N newest" across types. LESSON: counted-vmcnt
// pipelines must be single-type. This kernel (R12-verified, 321.4us,
// absmax 0.00390625) uses all-GLL staging:
//  - qkv: 192x128 blk, 4 waves, wave 96x64, ring-2 XOR-swizzled LDS 80KB
//    (2 desynced blocks/CU), WAIT_VM(10) steady (never drains mid-loop).
//  - proj: 128x128 blk, ring-2 48KB, WAIT_VM(6), 512 blocks = 2/CU.
//  - qkv sits AT the LDS-BW roofline for all-LDS staging (83 of 85 B/cyc,
//    m134): schedule tweaks (unpin/setprio/stagger) are null by design.
// Bit-exact accumulation order preserved (absmax = race detector).
//
// Workspace (peak 229 MiB): qkv fp32 @0; y fp32 @100663296; x_t_h/l fp16
// @201326592/@218103808 (dead after qkv GEMM); attout fp16 @201326592
// (overlays x_t); w_qkv_h/l @234881024; w_proj_h/l @238026752.
// vk stats (144 KB) live in d_out (proj GEMM fully overwrites d_out after).

#define NPIX 4096
#define TD3 1536

typedef _Float16 f16;
typedef __attribute__((ext_vector_type(8))) _Float16 v8h;
typedef __attribute__((ext_vector_type(4))) float v4f;

#define GLL16(g, l) __builtin_amdgcn_global_load_lds(                         \
    (const __attribute__((address_space(1))) unsigned int*)(g),               \
    (__attribute__((address_space(3))) unsigned int*)(l), 16, 0, 0)

#define WAIT_VM(n) asm volatile("s_waitcnt vmcnt(" #n ")" ::: "memory")
#define WAIT_LGKM0() asm volatile("s_waitcnt lgkmcnt(0)" ::: "memory")
#define SBAR() __builtin_amdgcn_s_barrier()
#define SCHED() __builtin_amdgcn_sched_barrier(0)

// per-block pseudo-random stagger: de-correlates co-resident blocks.
__device__ __forceinline__ void phase_stagger()
{
    unsigned bid = blockIdx.x + gridDim.x * (blockIdx.y + gridDim.y * blockIdx.z);
    unsigned d = (bid * 2654435761u) >> 27;   // top 5 bits of Knuth hash
    for (unsigned i = 0; i < d; ++i) asm volatile("s_sleep 2");
}

// ---------------------------------------------------------------------------
// qkv GEMM: C = Ah*Bh + Al*Bh + Ah*Bl. A=w_qkv (1536x512) hi/lo, B=x_t
// (4096x512) hi/lo, C (1536x4096) fp32, batched over z.
// 192x128 block, BK=32, 256 thr = 4 waves (2M x 2N), wave 96x64 (acc 6x4).
// Ring-2 XOR-swizzled LDS (80 KB, 2 blocks/CU) + counted vmcnt
// (10 GLL/thread/tile). Per iter: WAIT_VM(10) -> barrier ->
// {20 ds_reads + 72 MFMAs, compiler-interleaved} -> lgkmcnt(0) -> barrier
// -> stage(t+2). vmcnt never 0 until the last iter. All-GLL single-type
// FIFO (see header: mixed types race).
// ---------------------------------------------------------------------------
__global__ __launch_bounds__(256, 2) void gemm_qkv(
    const f16* __restrict__ Ah, const f16* __restrict__ Al,
    const f16* __restrict__ Bh, const f16* __restrict__ Bl,
    float* __restrict__ C)
{
    const int N = 4096, K = 512, KT = 16;
    __shared__ f16 AsH[2][192 * 32];   // 24 KB
    __shared__ f16 AsL[2][192 * 32];   // 24 KB
    __shared__ f16 BsH[2][128 * 32];   // 16 KB
    __shared__ f16 BsL[2][128 * 32];   // 16 KB  => 80 KB total

    const int tid = threadIdx.x;
    const int lane = tid & 63;
    const int w = tid >> 6;
    const int wm = w >> 1, wn = w & 1;
    const int mBase = blockIdx.y * 192, nBase = blockIdx.x * 128;
    Bh += (size_t)blockIdx.z * N * K;
    Bl += (size_t)blockIdx.z * N * K;
    C  += (size_t)blockIdx.z * 1536 * N;

    // staging chunks (1 KB = 64 lanes x 16B). A: 12 chunks, wave w gets
    // w*3..w*3+2; B: 8 chunks, wave w gets w*2,w*2+1. GLOBAL source is
    // pre-swizzled (logical = phys ^ (((phys>>7)&3)<<4)) so the linear GLL
    // dest + swizzled ds_read agree (rule #21; verified R2/R3/R6/R8).
    int aOff[3], ldsA[3], bOff[2], ldsB[2];
    #pragma unroll
    for (int p = 0; p < 3; ++p) {
        int c = w * 3 + p;
        int phys = c * 1024 + lane * 16;
        int lgc = phys ^ (((phys >> 7) & 3) << 4);
        aOff[p] = (mBase + (lgc >> 6)) * K + ((lgc & 63) >> 1);
        ldsA[p] = c * 512;
    }
    #pragma unroll
    for (int p = 0; p < 2; ++p) {
        int c = w * 2 + p;
        int phys = c * 1024 + lane * 16;
        int lgc = phys ^ (((phys >> 7) & 3) << 4);
        bOff[p] = (nBase + (lgc >> 6)) * K + ((lgc & 63) >> 1);
        ldsB[p] = c * 512;
    }

    const int kq = lane >> 4, rm = lane & 15;
    const int slot = kq ^ ((rm >> 1) & 3);   // conflict-free read slot

    v4f acc[6][4];
    #pragma unroll
    for (int i = 0; i < 6; ++i)
        #pragma unroll
        for (int j = 0; j < 4; ++j)
            acc[i][j] = (v4f){0.f, 0.f, 0.f, 0.f};

    auto stage = [&](int kt, int s) {
        const int ko = kt * 32;
        #pragma unroll
        for (int p = 0; p < 3; ++p) {
            GLL16(Ah + aOff[p] + ko, &AsH[s][ldsA[p]]);
            GLL16(Al + aOff[p] + ko, &AsL[s][ldsA[p]]);
        }
        #pragma unroll
        for (int p = 0; p < 2; ++p) {
            GLL16(Bh + bOff[p] + ko, &BsH[s][ldsB[p]]);
            GLL16(Bl + bOff[p] + ko, &BsL[s][ldsB[p]]);
        }
    };
    stage(0, 0);
    stage(1, 1);      // 20 loads in flight

    phase_stagger();  // de-correlate co-resident blocks (loads keep flying)

    for (int kt = 0; kt < KT; ++kt) {
        const int cs = kt & 1;
        // tile t landed; tile t+1's 10 loads stay IN FLIGHT (per-wave,
        // in-order retirement within the GLL type; single-type FIFO)
        if (kt < KT - 1) { WAIT_VM(10); } else { WAIT_VM(0); }
        SBAR(); SCHED();

        // reads + MFMAs: ONE compiler-scheduled region (fine lgkmcnt).
        v8h ah[6], al[6], bh[4], bl[4];
        #pragma unroll
        for (int i = 0; i < 6; ++i) {
            int rA = (wm * 96 + i * 16 + rm) * 32 + slot * 8;
            ah[i] = *(const v8h*)&AsH[cs][rA];
            al[i] = *(const v8h*)&AsL[cs][rA];
        }
        #pragma unroll
        for (int j = 0; j < 4; ++j) {
            int rB = (wn * 64 + j * 16 + rm) * 32 + slot * 8;
            bh[j] = *(const v8h*)&BsH[cs][rB];
            bl[j] = *(const v8h*)&BsL[cs][rB];
        }
        #pragma unroll
        for (int i = 0; i < 6; ++i)
            #pragma unroll
            for (int j = 0; j < 4; ++j) {
                acc[i][j] = __builtin_amdgcn_mfma_f32_16x16x32_f16(
                    ah[i], bh[j], acc[i][j], 0, 0, 0);
                acc[i][j] = __builtin_amdgcn_mfma_f32_16x16x32_f16(
                    al[i], bh[j], acc[i][j], 0, 0, 0);
                acc[i][j] = __builtin_amdgcn_mfma_f32_16x16x32_f16(
                    ah[i], bl[j], acc[i][j], 0, 0, 0);
            }

        // ring safety: all waves' reads of slot cs complete before the
        // overwrite below. lgkmcnt(0) is ~free (reads already consumed).
        WAIT_LGKM0();
        SBAR(); SCHED();
        if (kt + 2 < KT) stage(kt + 2, cs);   // lands during next iter
    }

    // epilogue: D row=(lane>>4)*4+reg, col=lane&15
    const int rq = lane >> 4, cn = lane & 15;
    #pragma unroll
    for (int i = 0; i < 6; ++i)
        #pragma unroll
        for (int rg = 0; rg < 4; ++rg) {
            int row = mBase + wm * 96 + i * 16 + rq * 4 + rg;
            #pragma unroll
            for (int j = 0; j < 4; ++j) {
                int col = nBase + wn * 64 + j * 16 + cn;
                C[(size_t)row * N + col] = acc[i][j][rg];
            }
        }
}

// ---------------------------------------------------------------------------
// proj GEMM + BN: C = BN(Ah*Bh + Al*Bh). A=w_proj (512x1024) hi/lo,
// B=attout (4096x1024) fp16, C (512x4096) fp32, batched over z.
// 128x128 block, BK=32, 256 thr = 4 waves (2M x 2N), wave 64x64 (acc 4x4).
// Ring-2 LDS = 48 KB -> 2 desynced blocks/CU; WAIT_VM(6) steady.
// ---------------------------------------------------------------------------
__global__ __launch_bounds__(256, 2) void gemm_proj(
    const f16* __restrict__ Ah, const f16* __restrict__ Al,
    const f16* __restrict__ Bh, float* __restrict__ C,
    const float* __restrict__ bn_g, const float* __restrict__ bn_b,
    const float* __restrict__ bn_m, const float* __restrict__ bn_v)
{
    const int N = 4096, K = 1024, KT = 32;
    __shared__ f16 AsH[2][128 * 32];   // 16 KB
    __shared__ f16 AsL[2][128 * 32];   // 16 KB
    __shared__ f16 BsH[2][128 * 32];   // 16 KB  => 48 KB total

    const int tid = threadIdx.x;
    const int lane = tid & 63;
    const int w = tid >> 6;
    const int wm = w >> 1, wn = w & 1;
    const int mBase = blockIdx.y * 128, nBase = blockIdx.x * 128;
    Bh += (size_t)blockIdx.z * N * K;
    C  += (size_t)blockIdx.z * 512 * N;

    // 8 chunks per 8KB tile; wave w does chunks w*2, w*2+1 (A and B).
    int aOff[2], ldsA[2], bOff[2], ldsB[2];
    #pragma unroll
    for (int p = 0; p < 2; ++p) {
        int c = w * 2 + p;
        int phys = c * 1024 + lane * 16;
        int lgc = phys ^ (((phys >> 7) & 3) << 4);
        aOff[p] = (mBase + (lgc >> 6)) * K + ((lgc & 63) >> 1);
        bOff[p] = (nBase + (lgc >> 6)) * K + ((lgc & 63) >> 1);
        ldsA[p] = c * 512;
        ldsB[p] = c * 512;
    }

    const int kq = lane >> 4, rm = lane & 15;
    const int slot = kq ^ ((rm >> 1) & 3);

    v4f acc[4][4];
    #pragma unroll
    for (int i = 0; i < 4; ++i)
        #pragma unroll
        for (int j = 0; j < 4; ++j)
            acc[i][j] = (v4f){0.f, 0.f, 0.f, 0.f};

    auto stage = [&](int kt, int s) {
        const int ko = kt * 32;
        #pragma unroll
        for (int p = 0; p < 2; ++p) {
            GLL16(Ah + aOff[p] + ko, &AsH[s][ldsA[p]]);
            GLL16(Al + aOff[p] + ko, &AsL[s][ldsA[p]]);
            GLL16(Bh + bOff[p] + ko, &BsH[s][ldsB[p]]);
        }
    };
    stage(0, 0);
    stage(1, 1);      // 12 loads in flight

    phase_stagger();

    for (int kt = 0; kt < KT; ++kt) {
        const int cs = kt & 1;
        if (kt < KT - 1) { WAIT_VM(6); } else { WAIT_VM(0); }
        SBAR(); SCHED();

        v8h ah[4], al[4], bh[4];
        #pragma unroll
        for (int i = 0; i < 4; ++i) {
            int rA = (wm * 64 + i * 16 + rm) * 32 + slot * 8;
            ah[i] = *(const v8h*)&AsH[cs][rA];
            al[i] = *(const v8h*)&AsL[cs][rA];
        }
        #pragma unroll
        for (int j = 0; j < 4; ++j) {
            int rB = (wn * 64 + j * 16 + rm) * 32 + slot * 8;
            bh[j] = *(const v8h*)&BsH[cs][rB];
        }
        #pragma unroll
        for (int i = 0; i < 4; ++i)
            #pragma unroll
            for (int j = 0; j < 4; ++j) {
                acc[i][j] = __builtin_amdgcn_mfma_f32_16x16x32_f16(
                    ah[i], bh[j], acc[i][j], 0, 0, 0);
                acc[i][j] = __builtin_amdgcn_mfma_f32_16x16x32_f16(
                    al[i], bh[j], acc[i][j], 0, 0, 0);
            }

        WAIT_LGKM0();
        SBAR(); SCHED();
        if (kt + 2 < KT) stage(kt + 2, cs);
    }

    const int rq = lane >> 4, cn = lane & 15;
    #pragma unroll
    for (int i = 0; i < 4; ++i)
        #pragma unroll
        for (int rg = 0; rg < 4; ++rg) {
            int row = mBase + wm * 64 + i * 16 + rq * 4 + rg;
            float sc = bn_g[row] * rsqrtf(bn_v[row] + 1e-5f);
            float sh = bn_b[row] - bn_m[row] * sc;
            #pragma unroll
            for (int j = 0; j < 4; ++j) {
                int col = nBase + wn * 64 + j * 16 + cn;
                C[(size_t)row * N + col] = acc[i][j][rg] * sc + sh;
            }
        }
}

// ---------------------------------------------------------------------------
// fp32 -> (fp16 hi, fp16 lo) for BOTH weight tensors in one launch.
// ---------------------------------------------------------------------------
__global__ __launch_bounds__(256) void cvt_split2(
    const float* __restrict__ s1, f16* __restrict__ d1h, f16* __restrict__ d1l,
    int n4_1,
    const float* __restrict__ s2, f16* __restrict__ d2h, f16* __restrict__ d2l,
    int n4_2)
{
    int i = blockIdx.x * 256 + threadIdx.x;
    const float* src; f16* dh; f16* dl; int idx;
    if (i < n4_1) { src = s1; dh = d1h; dl = d1l; idx = i; }
    else if (i < n4_1 + n4_2) { src = s2; dh = d2h; dl = d2l; idx = i - n4_1; }
    else return;
    float4 f = ((const float4*)src)[idx];
    f16 h[4], l[4];
    float ff[4] = {f.x, f.y, f.z, f.w};
    #pragma unroll
    for (int q = 0; q < 4; ++q) {
        h[q] = (f16)ff[q];
        l[q] = (f16)(ff[q] - (float)h[q]);
    }
    *(uint2*)&dh[(size_t)idx * 4] = *(uint2*)h;
    *(uint2*)&dl[(size_t)idx * 4] = *(uint2*)l;
}

// ---------------------------------------------------------------------------
// Transpose + split: x (b, c=512, n=4096) fp32 -> x_t_h/l (b, n, c) fp16.
// ---------------------------------------------------------------------------
__global__ __launch_bounds__(256) void transp_split(
    const float* __restrict__ src, f16* __restrict__ dh, f16* __restrict__ dl)
{
    __shared__ float t[64][65];
    const int tid = threadIdx.x;
    const int n0 = blockIdx.x * 64, c0 = blockIdx.y * 64, b = blockIdx.z;

    const int row = tid >> 2;
    const int nn  = (tid & 3) * 16;
    const float* sp = src + ((size_t)b * 512 + c0 + row) * NPIX + n0 + nn;
    #pragma unroll
    for (int q = 0; q < 4; ++q) {
        float4 f = *(const float4*)(sp + q * 4);
        t[row][nn + q * 4 + 0] = f.x;
        t[row][nn + q * 4 + 1] = f.y;
        t[row][nn + q * 4 + 2] = f.z;
        t[row][nn + q * 4 + 3] = f.w;
    }
    __syncthreads();

    const int nrow = tid >> 2;
    const int cc   = (tid & 3) * 16;
    f16 h[16], l[16];
    #pragma unroll
    for (int q = 0; q < 16; ++q) {
        float f = t[cc + q][nrow];
        h[q] = (f16)f;
        l[q] = (f16)(f - (float)h[q]);
    }
    size_t di = ((size_t)b * NPIX + n0 + nrow) * 512 + c0 + cc;
    *(uint4*)&dh[di] = *(uint4*)&h[0];
    *(uint4*)&dh[di + 8] = *(uint4*)&h[8];
    *(uint4*)&dl[di] = *(uint4*)&l[0];
    *(uint4*)&dl[di + 8] = *(uint4*)&l[8];
}

// ---------------------------------------------------------------------------
// Fused depthwise 5x5 conv (pad 2) + per-group 8x8 mix. (v2, proven)
// ---------------------------------------------------------------------------
__global__ __launch_bounds__(256) void dwpw(
    const float* __restrict__ qkv, const float* __restrict__ w_dw,
    const float* __restrict__ w_pw, float* __restrict__ y)
{
    __shared__ float tile[8][36][68];   // 78336 B -> 2 blocks/CU

    const int tid = threadIdx.x;
    const int g = blockIdx.y;
    const int b = blockIdx.z;
    const int h0 = blockIdx.x * 32;
    const size_t cbase = (size_t)b * TD3 + g * 8;

    for (int idx = tid; idx < 288; idx += 256) {
        int ch = idx / 36, r = idx - ch * 36;
        *(float2*)&tile[ch][r][0]  = (float2){0.f, 0.f};
        *(float2*)&tile[ch][r][66] = (float2){0.f, 0.f};
    }
    #pragma unroll
    for (int it = 0; it < 18; ++it) {
        int idx = tid + it * 256;
        int ch = idx / 576;
        int rem = idx - ch * 576;
        int r = rem >> 4, q = rem & 15;
        int gh = h0 + r - 2;
        float4 v = {0.f, 0.f, 0.f, 0.f};
        if (gh >= 0 && gh < 64)
            v = *(const float4*)&qkv[(cbase + ch) * NPIX + gh * 64 + q * 4];
        *(float2*)&tile[ch][r][2 + q * 4] = (float2){v.x, v.y};
        *(float2*)&tile[ch][r][4 + q * 4] = (float2){v.z, v.w};
    }
    __syncthreads();

    const int wc0 = (tid & 15) * 4;
    const int rp  = tid >> 4;

    float acc[8][8];
    #pragma unroll
    for (int o = 0; o < 8; ++o)
        #pragma unroll
        for (int p = 0; p < 8; ++p) acc[o][p] = 0.f;

    #pragma unroll
    for (int ch = 0; ch < 8; ++ch) {
        const float* wdg = w_dw + (size_t)(g * 8 + ch) * 25;
        float wdr[25];
        #pragma unroll
        for (int t = 0; t < 25; ++t) wdr[t] = wdg[t];
        float wpr[8];
        #pragma unroll
        for (int o = 0; o < 8; ++o) wpr[o] = w_pw[g * 64 + o * 8 + ch];

        float w[6][8];
        #pragma unroll
        for (int rr = 0; rr < 6; ++rr) {
            *(float4*)&w[rr][0] = *(const float4*)&tile[ch][rp * 2 + rr][wc0];
            *(float4*)&w[rr][4] = *(const float4*)&tile[ch][rp * 2 + rr][wc0 + 4];
        }

        float dwv[8];
        #pragma unroll
        for (int s = 0; s < 2; ++s)
            #pragma unroll
            for (int cc = 0; cc < 4; ++cc) {
                float sum = 0.f;
                #pragma unroll
                for (int di = 0; di < 5; ++di)
                    #pragma unroll
                    for (int dj = 0; dj < 5; ++dj)
                        sum = fmaf(w[s + di][cc + dj], wdr[di * 5 + dj], sum);
                dwv[s * 4 + cc] = sum;
            }
        #pragma unroll
        for (int o = 0; o < 8; ++o)
            #pragma unroll
            for (int p = 0; p < 8; ++p)
                acc[o][p] = fmaf(dwv[p], wpr[o], acc[o][p]);
    }

    #pragma unroll
    for (int o = 0; o < 8; ++o)
        #pragma unroll
        for (int s = 0; s < 2; ++s) {
            float4 v = {acc[o][s * 4 + 0], acc[o][s * 4 + 1],
                        acc[o][s * 4 + 2], acc[o][s * 4 + 3]};
            *(float4*)&y[(cbase + o) * NPIX + (h0 + rp * 2 + s) * 64 + wc0] = v;
        }
}

// ---------------------------------------------------------------------------
// Attention stats per (b,h): vk[9][8] = sum_n [v;1][d,n] * relu(k)[e,n]
// ---------------------------------------------------------------------------
__global__ __launch_bounds__(256) void attn_stats(
    const float* __restrict__ qkv, const float* __restrict__ yy,
    float* __restrict__ vkout)
{
    const int h = blockIdx.x;
    const int b = blockIdx.y;
    const float* src = (h < 64)
        ? qkv + ((size_t)b * TD3 + h * 24) * NPIX
        : yy  + ((size_t)b * TD3 + (h - 64) * 24) * NPIX;

    float acc[9][8];
    #pragma unroll
    for (int d = 0; d < 9; ++d)
        #pragma unroll
        for (int e = 0; e < 8; ++e) acc[d][e] = 0.f;

    for (int n = threadIdx.x; n < NPIX; n += 256) {
        float kr[8], vv[8];
        #pragma unroll
        for (int e = 0; e < 8; ++e) kr[e] = fmaxf(src[(8 + e) * NPIX + n], 0.f);
        #pragma unroll
        for (int d = 0; d < 8; ++d) vv[d] = src[(16 + d) * NPIX + n];
        #pragma unroll
        for (int d = 0; d < 8; ++d)
            #pragma unroll
            for (int e = 0; e < 8; ++e) acc[d][e] = fmaf(vv[d], kr[e], acc[d][e]);
        #pragma unroll
        for (int e = 0; e < 8; ++e) acc[8][e] += kr[e];
    }

    __shared__ float part[4][72];
    const int lane = threadIdx.x & 63, wave = threadIdx.x >> 6;
    #pragma unroll
    for (int i = 0; i < 72; ++i) {
        float v = acc[i / 8][i % 8];
        #pragma unroll
        for (int off = 32; off; off >>= 1) v += __shfl_down(v, off, 64);
        if (lane == 0) part[wave][i] = v;
    }
    __syncthreads();
    if (threadIdx.x < 72) {
        float v = part[0][threadIdx.x] + part[1][threadIdx.x] +
                  part[2][threadIdx.x] + part[3][threadIdx.x];
        vkout[((size_t)b * 128 + h) * 72 + threadIdx.x] = v;
    }
}

// ---------------------------------------------------------------------------
// Attention apply -> fp16, written transposed: attout[(b*4096+n)*1024+h*8+d]
// ---------------------------------------------------------------------------
__global__ __launch_bounds__(256) void attn_apply_t(
    const float* __restrict__ qkv, const float* __restrict__ yy,
    const float* __restrict__ vkin, f16* __restrict__ attout)
{
    const int h = blockIdx.y;
    const int b = blockIdx.z;
    const int n = blockIdx.x * 256 + threadIdx.x;

    __shared__ float vk[72];
    if (threadIdx.x < 72)
        vk[threadIdx.x] = vkin[((size_t)b * 128 + h) * 72 + threadIdx.x];
    __syncthreads();

    const float* src = (h < 64)
        ? qkv + ((size_t)b * TD3 + h * 24) * NPIX
        : yy  + ((size_t)b * TD3 + (h - 64) * 24) * NPIX;

    float qr[8];
    #pragma unroll
    for (int e = 0; e < 8; ++e) qr[e] = fmaxf(src[e * NPIX + n], 0.f);

    float den = 0.f;
    #pragma unroll
    for (int e = 0; e < 8; ++e) den = fmaf(vk[64 + e], qr[e], den);
    float inv = 1.f / (den + 1e-15f);

    f16 o[8];
    #pragma unroll
    for (int d = 0; d < 8; ++d) {
        float num = 0.f;
        #pragma unroll
        for (int e = 0; e < 8; ++e) num = fmaf(vk[d * 8 + e], qr[e], num);
        o[d] = (f16)(num * inv);
    }
    *(uint4*)&attout[((size_t)b * NPIX + n) * 1024 + h * 8] = *(uint4*)o;
}

// ---------------------------------------------------------------------------
extern "C" void kernel_launch(void* const* d_in, const int* in_sizes, int n_in,
                              void* d_out, int out_size, void* d_ws, size_t ws_size,
                              hipStream_t stream)
{
    (void)in_sizes; (void)n_in; (void)out_size; (void)ws_size;
    const float* x      = (const float*)d_in[0];
    const float* w_qkv  = (const float*)d_in[1];
    const float* w_dw   = (const float*)d_in[2];
    const float* w_pw   = (const float*)d_in[3];
    const float* w_proj = (const float*)d_in[4];
    const float* bn_g   = (const float*)d_in[5];
    const float* bn_b   = (const float*)d_in[6];
    const float* bn_m   = (const float*)d_in[7];
    const float* bn_v   = (const float*)d_in[8];
    float* out = (float*)d_out;

    char* ws = (char*)d_ws;
    float* qkv     = (float*)(ws);
    float* y       = (float*)(ws + 100663296);
    f16*   x_t_h   = (f16*)(ws + 201326592);    // dead after qkv GEMM
    f16*   x_t_l   = (f16*)(ws + 218103808);    // dead after qkv GEMM
    f16*   attout  = (f16*)(ws + 201326592);    // overlays x_t_h/l
    f16*   w_qkv_h = (f16*)(ws + 234881024);
    f16*   w_qkv_l = (f16*)(ws + 236453888);
    f16*   w_proj_h= (f16*)(ws + 238026752);
    f16*   w_proj_l= (f16*)(ws + 239075328);
    float* vk      = out;                        // scratch; proj overwrites

    // 0. split both weight tensors to fp16 hi/lo (one launch)
    cvt_split2<<<1280, 256, 0, stream>>>(
        w_qkv, w_qkv_h, w_qkv_l, 196608,
        w_proj, w_proj_h, w_proj_l, 131072);
    // 1. x (b,c,n) -> x_t (b,n,c) fp16 hi/lo
    transp_split<<<dim3(64, 8, 4), 256, 0, stream>>>(x, x_t_h, x_t_l);
    // 2. qkv = w_qkv @ x  (M=1536,N=4096,K=512, batch 4), 3-pass split
    gemm_qkv<<<dim3(32, 8, 4), 256, 0, stream>>>(
        w_qkv_h, w_qkv_l, x_t_h, x_t_l, qkv);
    // 3. y = groupmix(dwconv5x5(qkv)), 32-row tiles
    dwpw<<<dim3(2, 192, 4), 256, 0, stream>>>(qkv, w_dw, w_pw, y);
    // 4. attention stats -> vk (in d_out)
    attn_stats<<<dim3(128, 4), 256, 0, stream>>>(qkv, y, vk);
    // 5. attention apply -> attout (b,n,c) fp16 (overwrites dead x_t region)
    attn_apply_t<<<dim3(16, 128, 4), 256, 0, stream>>>(qkv, y, vk, attout);
    // 6. out = BN(w_proj @ attout)  (M=512,N=4096,K=1024, batch 4), 2-pass
    gemm_proj<<<dim3(32, 4, 4), 256, 0, stream>>>(
        w_proj_h, w_proj_l, attout, out, bn_g, bn_b, bn_m, bn_v);
}

// Round 15
// 297.489 us; speedup vs baseline: 1.0987x; 1.0987x over previous
//
#include <hip/hip_runtime.h>
#include <cstddef>

// LiteMLA: qkv GEMM (split-fp16 MFMA, 3-pass) -> dwconv5x5+groupmix ->
// linear attention -> proj GEMM (split-A fp16 MFMA, 2-pass) + BN.
// B=4, C=512, H=W=64, N=4096, heads=128, 24 ch/head.
//
// Precision design: attention's relu(q)/relu(k) sign decisions amplify GEMM
// rounding (bf16 1-pass -> absmax 0.07). Split fp16 (hi+lo) gives ~2^-22
// rel GEMM error on qkv GEMM; proj is linear so split-A only suffices.
// v15: INTERMEDIATE tensors qkv,y stored fp16 (halves ~300MB of HBM traffic
// across 4 kernels). Error analysis: qkv std~1.1, fp16 rel 2^-11 ->
// ~0.001-0.003 perturbation; attention ratio is homogeneous in q (errors
// mostly cancel); predicted absmax ~0.006-0.009 vs 0.013 threshold.
//
// GEMM v12 core (R8-R14 verified): all-GLL single-type counted-vmcnt FIFO
// (R13 lesson: vmcnt in-order only WITHIN a VMEM type -- never mix
// global_load and global_load_lds in one counted FIFO). qkv: 192x128 blk,
// ring-2 XOR-swizzled LDS 80KB, 2 desynced blocks/CU, WAIT_VM(10) steady.
// proj: 128x128 blk, ring-2 48KB, WAIT_VM(6), 512 blocks = 2/CU.
// qkv GEMM sits AT the LDS-feed roofline for this structure (83/85 B/cyc).
//
// Workspace (peak 139 MiB):
//   qkv f16      50331648 @ 0
//   y   f16      50331648 @ 50331648
//   x_t_h f16    16777216 @ 100663296  (dead after qkv GEMM)
//   x_t_l f16    16777216 @ 117440512  (dead after qkv GEMM)
//   attout f16   33554432 @ 100663296  (overlays x_t after it's dead)
//   w_qkv_h/l    1572864*2 @ 134217728
//   w_proj_h/l   1048576*2 @ 137363456
// vk stats (144 KB) live in d_out (proj GEMM fully overwrites d_out after).

#define NPIX 4096
#define TD3 1536

typedef _Float16 f16;
typedef __attribute__((ext_vector_type(8))) _Float16 v8h;
typedef __attribute__((ext_vector_type(2))) _Float16 v2h;
typedef __attribute__((ext_vector_type(4))) float v4f;

#define GLL16(g, l) __builtin_amdgcn_global_load_lds(                         \
    (const __attribute__((address_space(1))) unsigned int*)(g),               \
    (__attribute__((address_space(3))) unsigned int*)(l), 16, 0, 0)

#define WAIT_VM(n) asm volatile("s_waitcnt vmcnt(" #n ")" ::: "memory")
#define WAIT_LGKM0() asm volatile("s_waitcnt lgkmcnt(0)" ::: "memory")
#define SBAR() __builtin_amdgcn_s_barrier()
#define SCHED() __builtin_amdgcn_sched_barrier(0)

// per-block pseudo-random stagger: de-correlates co-resident blocks.
__device__ __forceinline__ void phase_stagger()
{
    unsigned bid = blockIdx.x + gridDim.x * (blockIdx.y + gridDim.y * blockIdx.z);
    unsigned d = (bid * 2654435761u) >> 27;   // top 5 bits of Knuth hash
    for (unsigned i = 0; i < d; ++i) asm volatile("s_sleep 2");
}

// ---------------------------------------------------------------------------
// qkv GEMM: C = Ah*Bh + Al*Bh + Ah*Bl. A=w_qkv (1536x512) hi/lo, B=x_t
// (4096x512) hi/lo, C (1536x4096) FP16, batched over z.
// 192x128 block, BK=32, 256 thr = 4 waves (2M x 2N), wave 96x64 (acc 6x4).
// Ring-2 XOR-swizzled LDS (80 KB, 2 blocks/CU) + counted vmcnt
// (10 GLL/thread/tile, single-type FIFO). Per iter: WAIT_VM(10) -> barrier
// -> {20 ds_reads + 72 MFMAs} -> lgkmcnt(0) -> barrier -> stage(t+2).
// ---------------------------------------------------------------------------
__global__ __launch_bounds__(256, 2) void gemm_qkv(
    const f16* __restrict__ Ah, const f16* __restrict__ Al,
    const f16* __restrict__ Bh, const f16* __restrict__ Bl,
    f16* __restrict__ C)
{
    const int N = 4096, K = 512, KT = 16;
    __shared__ f16 AsH[2][192 * 32];   // 24 KB
    __shared__ f16 AsL[2][192 * 32];   // 24 KB
    __shared__ f16 BsH[2][128 * 32];   // 16 KB
    __shared__ f16 BsL[2][128 * 32];   // 16 KB  => 80 KB total

    const int tid = threadIdx.x;
    const int lane = tid & 63;
    const int w = tid >> 6;
    const int wm = w >> 1, wn = w & 1;
    const int mBase = blockIdx.y * 192, nBase = blockIdx.x * 128;
    Bh += (size_t)blockIdx.z * N * K;
    Bl += (size_t)blockIdx.z * N * K;
    C  += (size_t)blockIdx.z * 1536 * N;

    int aOff[3], ldsA[3], bOff[2], ldsB[2];
    #pragma unroll
    for (int p = 0; p < 3; ++p) {
        int c = w * 3 + p;
        int phys = c * 1024 + lane * 16;
        int lgc = phys ^ (((phys >> 7) & 3) << 4);
        aOff[p] = (mBase + (lgc >> 6)) * K + ((lgc & 63) >> 1);
        ldsA[p] = c * 512;
    }
    #pragma unroll
    for (int p = 0; p < 2; ++p) {
        int c = w * 2 + p;
        int phys = c * 1024 + lane * 16;
        int lgc = phys ^ (((phys >> 7) & 3) << 4);
        bOff[p] = (nBase + (lgc >> 6)) * K + ((lgc & 63) >> 1);
        ldsB[p] = c * 512;
    }

    const int kq = lane >> 4, rm = lane & 15;
    const int slot = kq ^ ((rm >> 1) & 3);   // conflict-free read slot

    v4f acc[6][4];
    #pragma unroll
    for (int i = 0; i < 6; ++i)
        #pragma unroll
        for (int j = 0; j < 4; ++j)
            acc[i][j] = (v4f){0.f, 0.f, 0.f, 0.f};

    auto stage = [&](int kt, int s) {
        const int ko = kt * 32;
        #pragma unroll
        for (int p = 0; p < 3; ++p) {
            GLL16(Ah + aOff[p] + ko, &AsH[s][ldsA[p]]);
            GLL16(Al + aOff[p] + ko, &AsL[s][ldsA[p]]);
        }
        #pragma unroll
        for (int p = 0; p < 2; ++p) {
            GLL16(Bh + bOff[p] + ko, &BsH[s][ldsB[p]]);
            GLL16(Bl + bOff[p] + ko, &BsL[s][ldsB[p]]);
        }
    };
    stage(0, 0);
    stage(1, 1);      // 20 loads in flight

    phase_stagger();  // de-correlate co-resident blocks (loads keep flying)

    for (int kt = 0; kt < KT; ++kt) {
        const int cs = kt & 1;
        if (kt < KT - 1) { WAIT_VM(10); } else { WAIT_VM(0); }
        SBAR(); SCHED();

        v8h ah[6], al[6], bh[4], bl[4];
        #pragma unroll
        for (int i = 0; i < 6; ++i) {
            int rA = (wm * 96 + i * 16 + rm) * 32 + slot * 8;
            ah[i] = *(const v8h*)&AsH[cs][rA];
            al[i] = *(const v8h*)&AsL[cs][rA];
        }
        #pragma unroll
        for (int j = 0; j < 4; ++j) {
            int rB = (wn * 64 + j * 16 + rm) * 32 + slot * 8;
            bh[j] = *(const v8h*)&BsH[cs][rB];
            bl[j] = *(const v8h*)&BsL[cs][rB];
        }
        #pragma unroll
        for (int i = 0; i < 6; ++i)
            #pragma unroll
            for (int j = 0; j < 4; ++j) {
                acc[i][j] = __builtin_amdgcn_mfma_f32_16x16x32_f16(
                    ah[i], bh[j], acc[i][j], 0, 0, 0);
                acc[i][j] = __builtin_amdgcn_mfma_f32_16x16x32_f16(
                    al[i], bh[j], acc[i][j], 0, 0, 0);
                acc[i][j] = __builtin_amdgcn_mfma_f32_16x16x32_f16(
                    ah[i], bl[j], acc[i][j], 0, 0, 0);
            }

        WAIT_LGKM0();
        SBAR(); SCHED();
        if (kt + 2 < KT) stage(kt + 2, cs);   // lands during next iter
    }

    // epilogue: D row=(lane>>4)*4+reg, col=lane&15; fp16 output
    const int rq = lane >> 4, cn = lane & 15;
    #pragma unroll
    for (int i = 0; i < 6; ++i)
        #pragma unroll
        for (int rg = 0; rg < 4; ++rg) {
            int row = mBase + wm * 96 + i * 16 + rq * 4 + rg;
            #pragma unroll
            for (int j = 0; j < 4; ++j) {
                int col = nBase + wn * 64 + j * 16 + cn;
                C[(size_t)row * N + col] = (f16)acc[i][j][rg];
            }
        }
}

// ---------------------------------------------------------------------------
// proj GEMM + BN: C = BN(Ah*Bh + Al*Bh). A=w_proj (512x1024) hi/lo,
// B=attout (4096x1024) fp16, C (512x4096) fp32 (final output), batch z.
// 128x128 block, ring-2 LDS 48 KB -> 2 desynced blocks/CU; WAIT_VM(6).
// ---------------------------------------------------------------------------
__global__ __launch_bounds__(256, 2) void gemm_proj(
    const f16* __restrict__ Ah, const f16* __restrict__ Al,
    const f16* __restrict__ Bh, float* __restrict__ C,
    const float* __restrict__ bn_g, const float* __restrict__ bn_b,
    const float* __restrict__ bn_m, const float* __restrict__ bn_v)
{
    const int N = 4096, K = 1024, KT = 32;
    __shared__ f16 AsH[2][128 * 32];   // 16 KB
    __shared__ f16 AsL[2][128 * 32];   // 16 KB
    __shared__ f16 BsH[2][128 * 32];   // 16 KB  => 48 KB total

    const int tid = threadIdx.x;
    const int lane = tid & 63;
    const int w = tid >> 6;
    const int wm = w >> 1, wn = w & 1;
    const int mBase = blockIdx.y * 128, nBase = blockIdx.x * 128;
    Bh += (size_t)blockIdx.z * N * K;
    C  += (size_t)blockIdx.z * 512 * N;

    int aOff[2], ldsA[2], bOff[2], ldsB[2];
    #pragma unroll
    for (int p = 0; p < 2; ++p) {
        int c = w * 2 + p;
        int phys = c * 1024 + lane * 16;
        int lgc = phys ^ (((phys >> 7) & 3) << 4);
        aOff[p] = (mBase + (lgc >> 6)) * K + ((lgc & 63) >> 1);
        bOff[p] = (nBase + (lgc >> 6)) * K + ((lgc & 63) >> 1);
        ldsA[p] = c * 512;
        ldsB[p] = c * 512;
    }

    const int kq = lane >> 4, rm = lane & 15;
    const int slot = kq ^ ((rm >> 1) & 3);

    v4f acc[4][4];
    #pragma unroll
    for (int i = 0; i < 4; ++i)
        #pragma unroll
        for (int j = 0; j < 4; ++j)
            acc[i][j] = (v4f){0.f, 0.f, 0.f, 0.f};

    auto stage = [&](int kt, int s) {
        const int ko = kt * 32;
        #pragma unroll
        for (int p = 0; p < 2; ++p) {
            GLL16(Ah + aOff[p] + ko, &AsH[s][ldsA[p]]);
            GLL16(Al + aOff[p] + ko, &AsL[s][ldsA[p]]);
            GLL16(Bh + bOff[p] + ko, &BsH[s][ldsB[p]]);
        }
    };
    stage(0, 0);
    stage(1, 1);      // 12 loads in flight

    phase_stagger();

    for (int kt = 0; kt < KT; ++kt) {
        const int cs = kt & 1;
        if (kt < KT - 1) { WAIT_VM(6); } else { WAIT_VM(0); }
        SBAR(); SCHED();

        v8h ah[4], al[4], bh[4];
        #pragma unroll
        for (int i = 0; i < 4; ++i) {
            int rA = (wm * 64 + i * 16 + rm) * 32 + slot * 8;
            ah[i] = *(const v8h*)&AsH[cs][rA];
            al[i] = *(const v8h*)&AsL[cs][rA];
        }
        #pragma unroll
        for (int j = 0; j < 4; ++j) {
            int rB = (wn * 64 + j * 16 + rm) * 32 + slot * 8;
            bh[j] = *(const v8h*)&BsH[cs][rB];
        }
        #pragma unroll
        for (int i = 0; i < 4; ++i)
            #pragma unroll
            for (int j = 0; j < 4; ++j) {
                acc[i][j] = __builtin_amdgcn_mfma_f32_16x16x32_f16(
                    ah[i], bh[j], acc[i][j], 0, 0, 0);
                acc[i][j] = __builtin_amdgcn_mfma_f32_16x16x32_f16(
                    al[i], bh[j], acc[i][j], 0, 0, 0);
            }

        WAIT_LGKM0();
        SBAR(); SCHED();
        if (kt + 2 < KT) stage(kt + 2, cs);
    }

    const int rq = lane >> 4, cn = lane & 15;
    #pragma unroll
    for (int i = 0; i < 4; ++i)
        #pragma unroll
        for (int rg = 0; rg < 4; ++rg) {
            int row = mBase + wm * 64 + i * 16 + rq * 4 + rg;
            float sc = bn_g[row] * rsqrtf(bn_v[row] + 1e-5f);
            float sh = bn_b[row] - bn_m[row] * sc;
            #pragma unroll
            for (int j = 0; j < 4; ++j) {
                int col = nBase + wn * 64 + j * 16 + cn;
                C[(size_t)row * N + col] = acc[i][j][rg] * sc + sh;
            }
        }
}

// ---------------------------------------------------------------------------
// fp32 -> (fp16 hi, fp16 lo) for BOTH weight tensors in one launch.
// ---------------------------------------------------------------------------
__global__ __launch_bounds__(256) void cvt_split2(
    const float* __restrict__ s1, f16* __restrict__ d1h, f16* __restrict__ d1l,
    int n4_1,
    const float* __restrict__ s2, f16* __restrict__ d2h, f16* __restrict__ d2l,
    int n4_2)
{
    int i = blockIdx.x * 256 + threadIdx.x;
    const float* src; f16* dh; f16* dl; int idx;
    if (i < n4_1) { src = s1; dh = d1h; dl = d1l; idx = i; }
    else if (i < n4_1 + n4_2) { src = s2; dh = d2h; dl = d2l; idx = i - n4_1; }
    else return;
    float4 f = ((const float4*)src)[idx];
    f16 h[4], l[4];
    float ff[4] = {f.x, f.y, f.z, f.w};
    #pragma unroll
    for (int q = 0; q < 4; ++q) {
        h[q] = (f16)ff[q];
        l[q] = (f16)(ff[q] - (float)h[q]);
    }
    *(uint2*)&dh[(size_t)idx * 4] = *(uint2*)h;
    *(uint2*)&dl[(size_t)idx * 4] = *(uint2*)l;
}

// ---------------------------------------------------------------------------
// Transpose + split: x (b, c=512, n=4096) fp32 -> x_t_h/l (b, n, c) fp16.
// ---------------------------------------------------------------------------
__global__ __launch_bounds__(256) void transp_split(
    const float* __restrict__ src, f16* __restrict__ dh, f16* __restrict__ dl)
{
    __shared__ float t[64][65];
    const int tid = threadIdx.x;
    const int n0 = blockIdx.x * 64, c0 = blockIdx.y * 64, b = blockIdx.z;

    const int row = tid >> 2;
    const int nn  = (tid & 3) * 16;
    const float* sp = src + ((size_t)b * 512 + c0 + row) * NPIX + n0 + nn;
    #pragma unroll
    for (int q = 0; q < 4; ++q) {
        float4 f = *(const float4*)(sp + q * 4);
        t[row][nn + q * 4 + 0] = f.x;
        t[row][nn + q * 4 + 1] = f.y;
        t[row][nn + q * 4 + 2] = f.z;
        t[row][nn + q * 4 + 3] = f.w;
    }
    __syncthreads();

    const int nrow = tid >> 2;
    const int cc   = (tid & 3) * 16;
    f16 h[16], l[16];
    #pragma unroll
    for (int q = 0; q < 16; ++q) {
        float f = t[cc + q][nrow];
        h[q] = (f16)f;
        l[q] = (f16)(f - (float)h[q]);
    }
    size_t di = ((size_t)b * NPIX + n0 + nrow) * 512 + c0 + cc;
    *(uint4*)&dh[di] = *(uint4*)&h[0];
    *(uint4*)&dh[di + 8] = *(uint4*)&h[8];
    *(uint4*)&dl[di] = *(uint4*)&l[0];
    *(uint4*)&dl[di + 8] = *(uint4*)&l[8];
}

// ---------------------------------------------------------------------------
// Fused depthwise 5x5 conv (pad 2) + per-group 8x8 mix.
// v15: qkv and y are fp16. Staging reads 8-px v8h chunks (16B) and
// converts to f32 in the LDS tile; outputs written as fp16 uint2 (4 px).
// ---------------------------------------------------------------------------
__global__ __launch_bounds__(256) void dwpw(
    const f16* __restrict__ qkv, const float* __restrict__ w_dw,
    const float* __restrict__ w_pw, f16* __restrict__ y)
{
    __shared__ float tile[8][36][68];   // 78336 B -> 2 blocks/CU

    const int tid = threadIdx.x;
    const int g = blockIdx.y;
    const int b = blockIdx.z;
    const int h0 = blockIdx.x * 32;
    const size_t cbase = (size_t)b * TD3 + g * 8;

    // zero halo columns (global cols -2,-1 and 64,65 are image padding)
    for (int idx = tid; idx < 288; idx += 256) {
        int ch = idx / 36, r = idx - ch * 36;
        *(float2*)&tile[ch][r][0]  = (float2){0.f, 0.f};
        *(float2*)&tile[ch][r][66] = (float2){0.f, 0.f};
    }
    // interior: 8 ch x 36 rows x 8 chunks(8px) = 2304 -> 9 iters x 256
    #pragma unroll
    for (int it = 0; it < 9; ++it) {
        int idx = tid + it * 256;
        int ch = idx / 288;
        int rem = idx - ch * 288;
        int r = rem >> 3, q = rem & 7;
        int gh = h0 + r - 2;
        float f[8] = {0.f, 0.f, 0.f, 0.f, 0.f, 0.f, 0.f, 0.f};
        if (gh >= 0 && gh < 64) {
            v8h v = *(const v8h*)&qkv[(cbase + ch) * NPIX + gh * 64 + q * 8];
            #pragma unroll
            for (int k = 0; k < 8; ++k) f[k] = (float)v[k];
        }
        #pragma unroll
        for (int k = 0; k < 4; ++k)
            *(float2*)&tile[ch][r][2 + q * 8 + k * 2] =
                (float2){f[k * 2], f[k * 2 + 1]};
    }
    __syncthreads();

    const int wc0 = (tid & 15) * 4;      // output cols wc0..wc0+3
    const int rp  = tid >> 4;            // output rows rp*2, rp*2+1 (local)

    float acc[8][8];
    #pragma unroll
    for (int o = 0; o < 8; ++o)
        #pragma unroll
        for (int p = 0; p < 8; ++p) acc[o][p] = 0.f;

    #pragma unroll
    for (int ch = 0; ch < 8; ++ch) {
        const float* wdg = w_dw + (size_t)(g * 8 + ch) * 25;
        float wdr[25];
        #pragma unroll
        for (int t = 0; t < 25; ++t) wdr[t] = wdg[t];
        float wpr[8];
        #pragma unroll
        for (int o = 0; o < 8; ++o) wpr[o] = w_pw[g * 64 + o * 8 + ch];

        float w[6][8];
        #pragma unroll
        for (int rr = 0; rr < 6; ++rr) {
            *(float4*)&w[rr][0] = *(const float4*)&tile[ch][rp * 2 + rr][wc0];
            *(float4*)&w[rr][4] = *(const float4*)&tile[ch][rp * 2 + rr][wc0 + 4];
        }

        float dwv[8];
        #pragma unroll
        for (int s = 0; s < 2; ++s)
            #pragma unroll
            for (int cc = 0; cc < 4; ++cc) {
                float sum = 0.f;
                #pragma unroll
                for (int di = 0; di < 5; ++di)
                    #pragma unroll
                    for (int dj = 0; dj < 5; ++dj)
                        sum = fmaf(w[s + di][cc + dj], wdr[di * 5 + dj], sum);
                dwv[s * 4 + cc] = sum;
            }
        #pragma unroll
        for (int o = 0; o < 8; ++o)
            #pragma unroll
            for (int p = 0; p < 8; ++p)
                acc[o][p] = fmaf(dwv[p], wpr[o], acc[o][p]);
    }

    #pragma unroll
    for (int o = 0; o < 8; ++o)
        #pragma unroll
        for (int s = 0; s < 2; ++s) {
            f16 o2[4];
            #pragma unroll
            for (int cc = 0; cc < 4; ++cc) o2[cc] = (f16)acc[o][s * 4 + cc];
            *(uint2*)&y[(cbase + o) * NPIX + (h0 + rp * 2 + s) * 64 + wc0] =
                *(uint2*)o2;
        }
}

// ---------------------------------------------------------------------------
// Attention stats per (b,h): vk[9][8] = sum_n [v;1][d,n] * relu(k)[e,n]
// v15: fp16 sources, 2 px per thread (v2h loads keep 4B/instr).
// ---------------------------------------------------------------------------
__global__ __launch_bounds__(256) void attn_stats(
    const f16* __restrict__ qkv, const f16* __restrict__ yy,
    float* __restrict__ vkout)
{
    const int h = blockIdx.x;
    const int b = blockIdx.y;
    const f16* src = (h < 64)
        ? qkv + ((size_t)b * TD3 + h * 24) * NPIX
        : yy  + ((size_t)b * TD3 + (h - 64) * 24) * NPIX;

    float acc[9][8];
    #pragma unroll
    for (int d = 0; d < 9; ++d)
        #pragma unroll
        for (int e = 0; e < 8; ++e) acc[d][e] = 0.f;

    for (int n = threadIdx.x * 2; n < NPIX; n += 512) {
        float k0[8], k1[8], v0[8], v1[8];
        #pragma unroll
        for (int e = 0; e < 8; ++e) {
            v2h kk = *(const v2h*)&src[(8 + e) * NPIX + n];
            k0[e] = fmaxf((float)kk[0], 0.f);
            k1[e] = fmaxf((float)kk[1], 0.f);
        }
        #pragma unroll
        for (int d = 0; d < 8; ++d) {
            v2h vv = *(const v2h*)&src[(16 + d) * NPIX + n];
            v0[d] = (float)vv[0];
            v1[d] = (float)vv[1];
        }
        #pragma unroll
        for (int d = 0; d < 8; ++d)
            #pragma unroll
            for (int e = 0; e < 8; ++e)
                acc[d][e] = fmaf(v1[d], k1[e], fmaf(v0[d], k0[e], acc[d][e]));
        #pragma unroll
        for (int e = 0; e < 8; ++e) acc[8][e] += k0[e] + k1[e];
    }

    __shared__ float part[4][72];
    const int lane = threadIdx.x & 63, wave = threadIdx.x >> 6;
    #pragma unroll
    for (int i = 0; i < 72; ++i) {
        float v = acc[i / 8][i % 8];
        #pragma unroll
        for (int off = 32; off; off >>= 1) v += __shfl_down(v, off, 64);
        if (lane == 0) part[wave][i] = v;
    }
    __syncthreads();
    if (threadIdx.x < 72) {
        float v = part[0][threadIdx.x] + part[1][threadIdx.x] +
                  part[2][threadIdx.x] + part[3][threadIdx.x];
        vkout[((size_t)b * 128 + h) * 72 + threadIdx.x] = v;
    }
}

// ---------------------------------------------------------------------------
// Attention apply -> fp16, written transposed: attout[(b*4096+n)*1024+h*8+d]
// v15: fp16 sources.
// ---------------------------------------------------------------------------
__global__ __launch_bounds__(256) void attn_apply_t(
    const f16* __restrict__ qkv, const f16* __restrict__ yy,
    const float* __restrict__ vkin, f16* __restrict__ attout)
{
    const int h = blockIdx.y;
    const int b = blockIdx.z;
    const int n = blockIdx.x * 256 + threadIdx.x;

    __shared__ float vk[72];
    if (threadIdx.x < 72)
        vk[threadIdx.x] = vkin[((size_t)b * 128 + h) * 72 + threadIdx.x];
    __syncthreads();

    const f16* src = (h < 64)
        ? qkv + ((size_t)b * TD3 + h * 24) * NPIX
        : yy  + ((size_t)b * TD3 + (h - 64) * 24) * NPIX;

    float qr[8];
    #pragma unroll
    for (int e = 0; e < 8; ++e)
        qr[e] = fmaxf((float)src[e * NPIX + n], 0.f);

    float den = 0.f;
    #pragma unroll
    for (int e = 0; e < 8; ++e) den = fmaf(vk[64 + e], qr[e], den);
    float inv = 1.f / (den + 1e-15f);

    f16 o[8];
    #pragma unroll
    for (int d = 0; d < 8; ++d) {
        float num = 0.f;
        #pragma unroll
        for (int e = 0; e < 8; ++e) num = fmaf(vk[d * 8 + e], qr[e], num);
        o[d] = (f16)(num * inv);
    }
    *(uint4*)&attout[((size_t)b * NPIX + n) * 1024 + h * 8] = *(uint4*)o;
}

// ---------------------------------------------------------------------------
extern "C" void kernel_launch(void* const* d_in, const int* in_sizes, int n_in,
                              void* d_out, int out_size, void* d_ws, size_t ws_size,
                              hipStream_t stream)
{
    (void)in_sizes; (void)n_in; (void)out_size; (void)ws_size;
    const float* x      = (const float*)d_in[0];
    const float* w_qkv  = (const float*)d_in[1];
    const float* w_dw   = (const float*)d_in[2];
    const float* w_pw   = (const float*)d_in[3];
    const float* w_proj = (const float*)d_in[4];
    const float* bn_g   = (const float*)d_in[5];
    const float* bn_b   = (const float*)d_in[6];
    const float* bn_m   = (const float*)d_in[7];
    const float* bn_v   = (const float*)d_in[8];
    float* out = (float*)d_out;

    char* ws = (char*)d_ws;
    f16*   qkv     = (f16*)(ws);                 // 48 MB fp16
    f16*   y       = (f16*)(ws + 50331648);      // 48 MB fp16
    f16*   x_t_h   = (f16*)(ws + 100663296);     // dead after qkv GEMM
    f16*   x_t_l   = (f16*)(ws + 117440512);     // dead after qkv GEMM
    f16*   attout  = (f16*)(ws + 100663296);     // overlays x_t_h/l
    f16*   w_qkv_h = (f16*)(ws + 134217728);
    f16*   w_qkv_l = (f16*)(ws + 135790592);
    f16*   w_proj_h= (f16*)(ws + 137363456);
    f16*   w_proj_l= (f16*)(ws + 138412032);
    float* vk      = out;                        // scratch; proj overwrites

    // 0. split both weight tensors to fp16 hi/lo (one launch)
    cvt_split2<<<1280, 256, 0, stream>>>(
        w_qkv, w_qkv_h, w_qkv_l, 196608,
        w_proj, w_proj_h, w_proj_l, 131072);
    // 1. x (b,c,n) -> x_t (b,n,c) fp16 hi/lo
    transp_split<<<dim3(64, 8, 4), 256, 0, stream>>>(x, x_t_h, x_t_l);
    // 2. qkv = w_qkv @ x  (M=1536,N=4096,K=512, batch 4), 3-pass split
    gemm_qkv<<<dim3(32, 8, 4), 256, 0, stream>>>(
        w_qkv_h, w_qkv_l, x_t_h, x_t_l, qkv);
    // 3. y = groupmix(dwconv5x5(qkv)), 32-row tiles (fp16 in/out)
    dwpw<<<dim3(2, 192, 4), 256, 0, stream>>>(qkv, w_dw, w_pw, y);
    // 4. attention stats -> vk (in d_out)
    attn_stats<<<dim3(128, 4), 256, 0, stream>>>(qkv, y, vk);
    // 5. attention apply -> attout (b,n,c) fp16 (overwrites dead x_t region)
    attn_apply_t<<<dim3(16, 128, 4), 256, 0, stream>>>(qkv, y, vk, attout);
    // 6. out = BN(w_proj @ attout)  (M=512,N=4096,K=1024, batch 4), 2-pass
    gemm_proj<<<dim3(32, 4, 4), 256, 0, stream>>>(
        w_proj_h, w_proj_l, attout, out, bn_g, bn_b, bn_m, bn_v);
}